// Round 5
// baseline (215.680 us; speedup 1.0000x reference)
//
#include <hip/hip_runtime.h>

// SpatialCorrelationSampler: out[b,(dy+4)*9+(dx+4),y,x] =
//   sum_c f0[b,c,y,x]*f1[b,c,y+dy,x+dx], dy,dx in [-4,4], OOB=0.
// B=4 C=256 H=96 W=160 -> out (4,81,96,160) fp32.
//
// R9: R5/R6/R8 (ILP engineering) all <=0; R4 base runs 1 block/CU
// (grid 240!), 2.25 waves/SIMD, one convoy barrier group -> ~2800cyc/stage
// exposed latency no source-level pipelining fixes. R7's channel-split
// needed a combine (broke). Correct split axis = dy: a 3-wave block owns
// dy group dg (dy_idx = dg*3+w) and writes its 27 out-channels EXCLUSIVELY
// -> no combine. 18-row window, LDS 36.9KB -> 4 blocks/CU, 12 waves/CU of
// independent barrier groups; one block's compute hides another's drain.
// dg is fastest-varying in dispatch (blk,blk+8,blk+16 = same tile+XCD) so
// the 3 blocks stream the same f1 window through L2 concurrently.
// Wave w owns dy_idx=dg*3+w; 16x16 tile, RX=4, acc[9][4]=36 regs.

#define Bn 4
#define Cn 256
#define Hn 96
#define Wn 160
#define HWn (Hn * Wn)
#define NP 81
#define TY 16
#define TX 16
#define CCH 8                  // channels per stage
#define NSTAGE (Cn / CCH)      // 32
#define WROWS 18               // window rows per 3-wave block (16 + 2)
#define SEGS 6                 // float4 segments per 24-col window row
#define LROW 32                // padded+swizzled LDS row stride (floats)
#define F1C (WROWS * LROW)     // 576 floats per staged channel
#define BUF (CCH * F1C)        // 4608 floats per LDS buffer
#define NT 192                 // 3 waves
#define STG_TOT (CCH * WROWS * SEGS)  // 864 float4 per stage
#define F1STG (CCH * HWn / 4)  // float4 stride between stages in f1

__global__ __launch_bounds__(NT, 3) void corr_kernel(const float* __restrict__ f0,
                                                     const float* __restrict__ f1,
                                                     float* __restrict__ out) {
    __shared__ __align__(16) float lds[2 * BUF];  // 36864 B double buffer

    const int tid  = threadIdx.x;
    const int wave = tid >> 6;      // 0..2
    const int lane = tid & 63;
    const int r    = lane >> 2;     // 0..15 tile row
    const int g    = lane & 3;      // 0..3  col group of 4 px

    // 720 blocks = 8 XCDs x (30 tiles x 3 dy-groups), dg fastest-varying:
    // same-tile trio = blk, blk+8, blk+16 -> concurrent, same XCD.
    const int blk = blockIdx.x;
    const int xcd = blk & 7;
    const int idx = blk >> 3;           // 0..89
    const int it  = idx / 3;            // 0..29 tile within XCD
    const int dg  = idx % 3;            // 0..2  dy group
    const int b   = xcd >> 1;
    const int ty  = (xcd & 1) * 3 + it / 10;
    const int tx  = it % 10;
    const int y0  = ty * TY;
    const int x0  = tx * TX;
    const int dg3 = dg * 3;

    // ---- staging map: 864 float4/stage over 192 thr = 4.5/thr ->
    // 5 unrolled slots, slot k handles idx k*192+tid (k=4: tid<96 only).
    int  slidx[5], sgidx[5];
    bool sval[5];
#pragma unroll
    for (int k = 0; k < 5; ++k) {
        const int ii  = k * NT + tid;
        const bool in = (k < 4) || (tid < STG_TOT - 4 * NT);   // ii < 864
        const int scc = ii / (WROWS * SEGS);                   // 0..7
        const int rem = ii - scc * (WROWS * SEGS);
        const int l   = rem / SEGS;                            // 0..17
        const int seg = rem - l * SEGS;                        // 0..5
        const int gy  = y0 - 4 + dg3 + l;
        const int gx  = x0 - 4 + seg * 4;    // mult of 4 -> all-in/out of [0,W)
        sval[k]  = in && (gy >= 0) && (gy < Hn) && (gx >= 0) && (gx < Wn);
        const int swz = (seg * 4) ^ ((l & 1) << 4);            // XOR-16 parity swizzle
        slidx[k] = (scc * F1C + l * LROW + swz) >> 2;          // float4 idx
        sgidx[k] = sval[k] ? ((((b * Cn + scc) * Hn + gy) * Wn + gx) >> 2) : 0;
        if (!in) slidx[k] = 0;   // never stored (guarded below)
    }
    const bool in4 = (tid < STG_TOT - 4 * NT);

    const float4* __restrict__ f1v = (const float4*)f1;
    float4* lv = (float4*)lds;

    // ---- read offsets (swizzle folded in, constant per lane)
    const int q  = r + wave;                      // 0..17 local window row
    const int xr = (q & 1) << 4;
    const int o0 = q * LROW + ((g * 4) ^ xr);
    const int o1 = q * LROW + ((g * 4 + 4) ^ xr);
    const int o2 = q * LROW + ((g * 4 + 8) ^ xr);

    // ---- prologue: prefetch stage 0
    float4 p1[5];
#pragma unroll
    for (int k = 0; k < 5; ++k) {
        p1[k] = make_float4(0.f, 0.f, 0.f, 0.f);
        if (sval[k]) p1[k] = f1v[sgidx[k]];
    }
    const float* f0s = f0 + ((b * Cn) * Hn + y0 + r) * Wn + x0 + g * 4;
    float4 p0[CCH];
#pragma unroll
    for (int cc = 0; cc < CCH; ++cc) p0[cc] = *(const float4*)(f0s + cc * HWn);

    float acc[9][4];
#pragma unroll
    for (int i = 0; i < 9; ++i)
#pragma unroll
        for (int j = 0; j < 4; ++j) acc[i][j] = 0.f;

    for (int s = 0; s < NSTAGE; ++s) {
        // publish stage s's f1 to buffer (s&1)
        float4* buf = lv + (s & 1) * (BUF / 4);
#pragma unroll
        for (int k = 0; k < 4; ++k) buf[slidx[k]] = p1[k];
        if (in4) buf[slidx[4]] = p1[4];
        __syncthreads();              // single barrier per stage

        // depth-1 prefetch for stage s+1 (in flight across compute)
        const int ns = (s + 1 < NSTAGE) ? s + 1 : NSTAGE - 1;
#pragma unroll
        for (int k = 0; k < 5; ++k) {
            float4 t = make_float4(0.f, 0.f, 0.f, 0.f);
            if (sval[k]) t = f1v[sgidx[k] + ns * F1STG];
            p1[k] = t;
        }
        float4 n0[CCH];
#pragma unroll
        for (int cc = 0; cc < CCH; ++cc)
            n0[cc] = *(const float4*)(f0s + (ns * CCH + cc) * HWn);

        // compute stage s
        const float* base = &lds[(s & 1) * BUF];
#pragma unroll
        for (int cc = 0; cc < CCH; ++cc) {
            const float* wr = base + cc * F1C;
            float4 w0 = *(const float4*)(wr + o0);
            float4 w1 = *(const float4*)(wr + o1);
            float4 w2 = *(const float4*)(wr + o2);
            float av[4]  = {p0[cc].x, p0[cc].y, p0[cc].z, p0[cc].w};
            float wv[12] = {w0.x, w0.y, w0.z, w0.w, w1.x, w1.y, w1.z, w1.w,
                            w2.x, w2.y, w2.z, w2.w};
#pragma unroll
            for (int dx = 0; dx < 9; ++dx)
#pragma unroll
                for (int rx = 0; rx < 4; ++rx)
                    acc[dx][rx] = fmaf(av[rx], wv[rx + dx], acc[dx][rx]);
        }

#pragma unroll
        for (int cc = 0; cc < CCH; ++cc) p0[cc] = n0[cc];
    }

    // ---- epilogue: block owns dy_idx = dg*3+wave -> 9 exclusive channels
    const int dyi  = dg3 + wave;
    const int orow = ((b * NP + dyi * 9) * Hn + y0 + r) * Wn + x0 + g * 4;
#pragma unroll
    for (int dx = 0; dx < 9; ++dx)
        *(float4*)(out + orow + dx * HWn) =
            make_float4(acc[dx][0], acc[dx][1], acc[dx][2], acc[dx][3]);
}

extern "C" void kernel_launch(void* const* d_in, const int* in_sizes, int n_in,
                              void* d_out, int out_size, void* d_ws, size_t ws_size,
                              hipStream_t stream) {
    const float* f0 = (const float*)d_in[0];
    const float* f1 = (const float*)d_in[1];
    float* out = (float*)d_out;
    corr_kernel<<<dim3(720), NT, 0, stream>>>(f0, f1, out);
}

// Round 7
// 183.468 us; speedup vs baseline: 1.1756x; 1.1756x over previous
//
#include <hip/hip_runtime.h>

// SpatialCorrelationSampler: out[b,(dy+4)*9+(dx+4),y,x] =
//   sum_c f0[b,c,y,x]*f1[b,c,y+dy,x+dx], dy,dx in [-4,4], OOB=0.
// B=4 C=256 H=96 W=160 -> out (4,81,96,160) fp32.
//
// R11: write-behind ping-pong. R4's stage = [18 conflicted ds_writes ~1200cyc,
// VALU idle] -> barrier -> [reads+FMA ~2600]: the write phase is serial dead
// time because it targets the buffer compute is about to read. R6 proved
// barrier-drain latency is NOT the main idle (async f0 didn't help), so the
// lever is the serial write phase itself. Change: during stage s's compute of
// buf[s&1], write stage s+1's f1 into buf[(s+1)&1]. Safety: that buffer was
// last read in stage s-1; the barrier ending s-1 separates those reads from
// these writes; stage s+1 reads after the barrier ending s. One barrier per
// stage still, but writes overlap compute on the LDS pipe. f1 prefetch depth
// 2 (+16 VGPR). Everything else identical to R4 (86.8us) for attribution.
// No workspace, no inter-block sync (R7/R10 lesson). Grid 240, 1 block/CU.
// Wave w owns dy = w-4; 16x16 tile, RX=4, acc[9][4]=36 regs.

#define Bn 4
#define Cn 256
#define Hn 96
#define Wn 160
#define HWn (Hn * Wn)
#define NP 81
#define TY 16
#define TX 16
#define CCH 8                 // channels per stage
#define NSTAGE (Cn / CCH)     // 32
#define WROWS (TY + 8)        // 24
#define SEGS 6                // float4 segments per 24-float data row
#define LROW 32               // padded+swizzled LDS row stride (floats)
#define F1C (WROWS * LROW)    // 768 floats per staged channel
#define BUF (CCH * F1C)       // 6144 floats per LDS buffer
#define NT 576                // 9 waves
#define F1STG (CCH * HWn / 4) // float4 stride between stages in f1

__global__ __launch_bounds__(NT, 2) void corr_kernel(const float* __restrict__ f0,
                                                     const float* __restrict__ f1,
                                                     float* __restrict__ out) {
    __shared__ __align__(16) float lds[2 * BUF];  // 49152 B double buffer

    const int tid  = threadIdx.x;
    const int wave = tid >> 6;      // 0..8 (dy = wave-4)
    const int lane = tid & 63;
    const int r    = lane >> 2;     // 0..15 tile row
    const int g    = lane & 3;      // 0..3  col group of 4 px

    // XCD-spatial swizzle: 240 blocks = 8 XCDs x 30 tiles (half-batch each).
    const int blk = blockIdx.x;
    const int xcd = blk & 7;
    const int it  = blk >> 3;           // 0..29
    const int b   = xcd >> 1;
    const int ty  = (xcd & 1) * 3 + it / 10;
    const int tx  = it % 10;
    const int y0  = ty * TY;
    const int x0  = tx * TX;

    // ---- staging map: 2 float4/thread/stage; copy 2 = same spot, channel +4
    const int scc  = tid / (WROWS * SEGS);        // 0..3
    const int srm  = tid - scc * (WROWS * SEGS);
    const int srr  = srm / SEGS;                  // 0..23 window row
    const int sseg = srm - srr * SEGS;            // 0..5
    const int sgy  = y0 - 4 + srr;
    const int sgx  = x0 - 4 + sseg * 4;           // mult of 4 -> seg all-in/out of [0,W)
    const bool sval = (sgy >= 0) && (sgy < Hn) && (sgx >= 0) && (sgx < Wn);
    const int swz   = (sseg * 4) ^ ((srr & 1) << 4);              // XOR-16 row-parity swizzle
    const int slidx = (scc * F1C + srr * LROW + swz) >> 2;        // float4 idx
    const int sgidx = sval ? ((((b * Cn + scc) * Hn + sgy) * Wn + sgx) >> 2) : 0;

    const float4* __restrict__ f1v = (const float4*)f1;
    float4* lv = (float4*)lds;

    // ---- read offsets (swizzle folded in; conflict-free: per 8-lane phase
    // rows q/q+1 give disjoint quad sets for each of o0/o1/o2)
    const int q  = r + wave;                      // 0..23 window row
    const int xr = (q & 1) << 4;
    const int o0 = q * LROW + ((g * 4) ^ xr);
    const int o1 = q * LROW + ((g * 4 + 4) ^ xr);
    const int o2 = q * LROW + ((g * 4 + 8) ^ xr);

    // ---- prologue: load stage 0 and stage 1 f1; publish stage 0 now
    float4 c1a = make_float4(0.f, 0.f, 0.f, 0.f), c1b = c1a;   // stage 0
    float4 w1a = c1a, w1b = c1a;                               // stage 1
    if (sval) {
        c1a = f1v[sgidx];            c1b = f1v[sgidx + HWn];
        w1a = f1v[sgidx + F1STG];    w1b = f1v[sgidx + F1STG + HWn];
    }
    lv[slidx]       = c1a;
    lv[slidx + F1C] = c1b;

    const float* f0s = f0 + ((b * Cn) * Hn + y0 + r) * Wn + x0 + g * 4;
    float4 p0[CCH];
#pragma unroll
    for (int cc = 0; cc < CCH; ++cc) p0[cc] = *(const float4*)(f0s + cc * HWn);

    float acc[9][4];
#pragma unroll
    for (int i = 0; i < 9; ++i)
#pragma unroll
        for (int j = 0; j < 4; ++j) acc[i][j] = 0.f;

    __syncthreads();

    for (int s = 0; s < NSTAGE; ++s) {
        // issue f1 prefetch for stage s+2 (full 2-stage flight time)
        const int ns2 = (s + 2 < NSTAGE) ? s + 2 : NSTAGE - 1;
        float4 l1a = make_float4(0.f, 0.f, 0.f, 0.f), l1b = l1a;
        if (sval) { l1a = f1v[sgidx + ns2 * F1STG]; l1b = f1v[sgidx + ns2 * F1STG + HWn]; }

        // f0 prefetch for stage s+1 (register diamond, same as R4)
        const int ns = (s + 1 < NSTAGE) ? s + 1 : NSTAGE - 1;
        float4 n0[CCH];
#pragma unroll
        for (int cc = 0; cc < CCH; ++cc)
            n0[cc] = *(const float4*)(f0s + (ns * CCH + cc) * HWn);

        // compute stage s from buf[s&1] (written during stage s-1)
        const float* base = &lds[(s & 1) * BUF];
#pragma unroll
        for (int cc = 0; cc < CCH; ++cc) {
            const float* wr = base + cc * F1C;
            float4 w0 = *(const float4*)(wr + o0);
            float4 w1 = *(const float4*)(wr + o1);
            float4 w2 = *(const float4*)(wr + o2);
            float av[4]  = {p0[cc].x, p0[cc].y, p0[cc].z, p0[cc].w};
            float wv[12] = {w0.x, w0.y, w0.z, w0.w, w1.x, w1.y, w1.z, w1.w,
                            w2.x, w2.y, w2.z, w2.w};
#pragma unroll
            for (int dx = 0; dx < 9; ++dx)
#pragma unroll
                for (int rx = 0; rx < 4; ++rx)
                    acc[dx][rx] = fmaf(av[rx], wv[rx + dx], acc[dx][rx]);
        }

        // write-behind: publish stage s+1's f1 into buf[(s+1)&1].
        // Safe: that buffer was last read in stage s-1 (same parity),
        // separated from these writes by the barrier ending s-1.
        if (s + 1 < NSTAGE) {
            float4* nbuf = lv + ((s + 1) & 1) * (BUF / 4);
            nbuf[slidx]       = w1a;
            nbuf[slidx + F1C] = w1b;
        }
        __syncthreads();

        w1a = l1a; w1b = l1b;
#pragma unroll
        for (int cc = 0; cc < CCH; ++cc) p0[cc] = n0[cc];
    }

    // ---- epilogue: exclusive ownership -> plain coalesced float4 stores
    const int orow = ((b * NP + wave * 9) * Hn + y0 + r) * Wn + x0 + g * 4;
#pragma unroll
    for (int dx = 0; dx < 9; ++dx)
        *(float4*)(out + orow + dx * HWn) =
            make_float4(acc[dx][0], acc[dx][1], acc[dx][2], acc[dx][3]);
}

extern "C" void kernel_launch(void* const* d_in, const int* in_sizes, int n_in,
                              void* d_out, int out_size, void* d_ws, size_t ws_size,
                              hipStream_t stream) {
    const float* f0 = (const float*)d_in[0];
    const float* f1 = (const float*)d_in[1];
    float* out = (float*)d_out;
    corr_kernel<<<dim3(240), NT, 0, stream>>>(f0, f1, out);
}

// Round 8
// 175.536 us; speedup vs baseline: 1.2287x; 1.0452x over previous
//
#include <hip/hip_runtime.h>

// SpatialCorrelationSampler: out[b,(dy+4)*9+(dx+4),y,x] =
//   sum_c f0[b,c,y,x]*f1[b,c,y+dy,x+dx], dy,dx in [-4,4], OOB=0.
// B=4 C=256 H=96 W=160 -> out (4,81,96,160) fp32.
//
// R12: conflict-counter solved across R4/R6/R9: 4 extra cyc/ds_read_b128 +
// 8/ds_write_b128, layout-invariant -> NO fixable conflicts; LDS busy
// ~2880cy/stage. Serial sum VALU 1820 + LDS 2880 + TA/drain 1300 ~= 6510
// measured -> nothing overlaps. Per-channel chain: 3 reads (~140cy
// service+latency at 2.25 waves/SIMD) vs 72cy FMA window -> R5's depth-1
// read-ahead covered only half; depth-3 covers it. Changes vs R4:
//  (1) depth-3 LDS read pipeline (preload ch0-2; FMA(cc) then reload
//      slot cc%3 with window cc+3; fully unrolled, static idx).
//  (2) f0 next-stage load issued right after FMA(cc)'s last use of
//      p0[cc] -> no n0[] buffer, f0 issue spread across phase.
//  (3) f1 prefetch issued right after barrier, pinned by ONE
//      sched_barrier(0) (not R8's whole-block pin).
// launch_bounds(576,3) caps VGPR<=170 so {3,2,2,2} placement fits.
// Wave w owns dy = w-4; 16x16 tile, RX=4, acc[9][4]=36 regs.

#define Bn 4
#define Cn 256
#define Hn 96
#define Wn 160
#define HWn (Hn * Wn)
#define NP 81
#define TY 16
#define TX 16
#define CCH 8                 // channels per stage
#define NSTAGE (Cn / CCH)     // 32
#define WROWS (TY + 8)        // 24
#define SEGS 6                // float4 segments per 24-float data row
#define LROW 32               // padded+swizzled LDS row stride (floats)
#define F1C (WROWS * LROW)    // 768 floats per staged channel
#define BUF (CCH * F1C)       // 6144 floats per LDS buffer
#define NT 576                // 9 waves
#define F1STG (CCH * HWn / 4) // float4 stride between stages in f1

__global__ __launch_bounds__(NT, 3) void corr_kernel(const float* __restrict__ f0,
                                                     const float* __restrict__ f1,
                                                     float* __restrict__ out) {
    __shared__ __align__(16) float lds[2 * BUF];  // 49152 B double buffer

    const int tid  = threadIdx.x;
    const int wave = tid >> 6;      // 0..8 (dy = wave-4)
    const int lane = tid & 63;
    const int r    = lane >> 2;     // 0..15 tile row
    const int g    = lane & 3;      // 0..3  col group of 4 px

    // XCD-spatial swizzle: 240 blocks = 8 XCDs x 30 tiles (half-batch each).
    const int blk = blockIdx.x;
    const int xcd = blk & 7;
    const int it  = blk >> 3;           // 0..29
    const int b   = xcd >> 1;
    const int ty  = (xcd & 1) * 3 + it / 10;
    const int tx  = it % 10;
    const int y0  = ty * TY;
    const int x0  = tx * TX;

    // ---- staging map: 2 float4/thread/stage; copy 2 = same spot, channel +4
    const int scc  = tid / (WROWS * SEGS);        // 0..3
    const int srm  = tid - scc * (WROWS * SEGS);
    const int srr  = srm / SEGS;                  // 0..23 window row
    const int sseg = srm - srr * SEGS;            // 0..5
    const int sgy  = y0 - 4 + srr;
    const int sgx  = x0 - 4 + sseg * 4;           // mult of 4 -> seg all-in/out of [0,W)
    const bool sval = (sgy >= 0) && (sgy < Hn) && (sgx >= 0) && (sgx < Wn);
    const int swz   = (sseg * 4) ^ ((srr & 1) << 4);              // XOR-16 row-parity swizzle
    const int slidx = (scc * F1C + srr * LROW + swz) >> 2;        // float4 idx
    const int sgidx = sval ? ((((b * Cn + scc) * Hn + sgy) * Wn + sgx) >> 2) : 0;

    const float4* __restrict__ f1v = (const float4*)f1;
    float4* lv = (float4*)lds;

    // ---- read offsets (swizzle folded in; uniform bank-quad coverage)
    const int q  = r + wave;                      // 0..23 window row
    const int xr = (q & 1) << 4;
    const int o0 = q * LROW + ((g * 4) ^ xr);
    const int o1 = q * LROW + ((g * 4 + 4) ^ xr);
    const int o2 = q * LROW + ((g * 4 + 8) ^ xr);

    // ---- prologue: prefetch stage 0
    float4 p1a = make_float4(0.f, 0.f, 0.f, 0.f), p1b = p1a;
    if (sval) { p1a = f1v[sgidx]; p1b = f1v[sgidx + HWn]; }   // ch scc, scc+4

    const float* f0s = f0 + ((b * Cn) * Hn + y0 + r) * Wn + x0 + g * 4;
    float4 p0[CCH];
#pragma unroll
    for (int cc = 0; cc < CCH; ++cc) p0[cc] = *(const float4*)(f0s + cc * HWn);

    float acc[9][4];
#pragma unroll
    for (int i = 0; i < 9; ++i)
#pragma unroll
        for (int j = 0; j < 4; ++j) acc[i][j] = 0.f;

    for (int s = 0; s < NSTAGE; ++s) {
        // publish stage s's f1 to buffer (s&1)
        float4* buf = lv + (s & 1) * (BUF / 4);
        buf[slidx]       = p1a;
        buf[slidx + F1C] = p1b;       // channel +4 -> +F1C float4
        __syncthreads();              // single barrier per stage

        // f1 prefetch for stage s+1: issue NOW, pin issue point (full
        // phase of flight time before use at next stage's top).
        const int ns = (s + 1 < NSTAGE) ? s + 1 : NSTAGE - 1;
        float4 t1a = make_float4(0.f, 0.f, 0.f, 0.f), t1b = t1a;
        if (sval) { t1a = f1v[sgidx + ns * F1STG]; t1b = f1v[sgidx + ns * F1STG + HWn]; }
        __builtin_amdgcn_sched_barrier(0);

        // depth-3 LDS read pipeline: preload windows for ch 0..2
        const float* base = &lds[(s & 1) * BUF];
        float4 wq[3][3];
#pragma unroll
        for (int k = 0; k < 3; ++k) {
            const float* wr = base + k * F1C;
            wq[k][0] = *(const float4*)(wr + o0);
            wq[k][1] = *(const float4*)(wr + o1);
            wq[k][2] = *(const float4*)(wr + o2);
        }

#pragma unroll
        for (int cc = 0; cc < CCH; ++cc) {
            const int sl = cc % 3;    // constant after unroll (static idx)
            float av[4]  = {p0[cc].x, p0[cc].y, p0[cc].z, p0[cc].w};
            float wv[12] = {wq[sl][0].x, wq[sl][0].y, wq[sl][0].z, wq[sl][0].w,
                            wq[sl][1].x, wq[sl][1].y, wq[sl][1].z, wq[sl][1].w,
                            wq[sl][2].x, wq[sl][2].y, wq[sl][2].z, wq[sl][2].w};
#pragma unroll
            for (int dx = 0; dx < 9; ++dx)
#pragma unroll
                for (int rx = 0; rx < 4; ++rx)
                    acc[dx][rx] = fmaf(av[rx], wv[rx + dx], acc[dx][rx]);
            // f0 for stage s+1, channel cc: p0[cc] dead after the FMAs
            // above (program order -> VALU reads before load writeback).
            p0[cc] = *(const float4*)(f0s + (ns * CCH + cc) * HWn);
            // refill slot with window for channel cc+3 (depth-3)
            if (cc + 3 < CCH) {
                const float* wr = base + (cc + 3) * F1C;
                wq[sl][0] = *(const float4*)(wr + o0);
                wq[sl][1] = *(const float4*)(wr + o1);
                wq[sl][2] = *(const float4*)(wr + o2);
            }
        }

        p1a = t1a; p1b = t1b;
    }

    // ---- epilogue: exclusive ownership -> plain coalesced float4 stores
    const int orow = ((b * NP + wave * 9) * Hn + y0 + r) * Wn + x0 + g * 4;
#pragma unroll
    for (int dx = 0; dx < 9; ++dx)
        *(float4*)(out + orow + dx * HWn) =
            make_float4(acc[dx][0], acc[dx][1], acc[dx][2], acc[dx][3]);
}

extern "C" void kernel_launch(void* const* d_in, const int* in_sizes, int n_in,
                              void* d_out, int out_size, void* d_ws, size_t ws_size,
                              hipStream_t stream) {
    const float* f0 = (const float*)d_in[0];
    const float* f1 = (const float*)d_in[1];
    float* out = (float*)d_out;
    corr_kernel<<<dim3(240), NT, 0, stream>>>(f0, f1, out);
}